// Round 5
// baseline (369.328 us; speedup 1.0000x reference)
//
#include <hip/hip_runtime.h>
#include <hip/hip_bf16.h>
#include <math.h>

#define B_  2
#define D_  8
#define H_  56
#define W_  56
#define C_  256
#define NH_ 8
#define HD_ 32
#define N_  98
#define NWIN_TOT 512
#define TOK (B_*D_*H_*W_)   // 50176
#define HID 1024

typedef short bf16x8 __attribute__((ext_vector_type(8)));
typedef float f32x4  __attribute__((ext_vector_type(4)));

__device__ __forceinline__ ushort f2b(float f) {
    union { float f; unsigned u; } v; v.f = f;
    unsigned r = v.u + 0x7fff + ((v.u >> 16) & 1);
    return (ushort)(r >> 16);
}
__device__ __forceinline__ float b2f(ushort h) {
    union { unsigned u; float f; } v; v.u = ((unsigned)h) << 16;
    return v.f;
}

__device__ __forceinline__ void glds16(const void* gsrc, void* lds_dst) {
    __builtin_amdgcn_global_load_lds(
        (const __attribute__((address_space(1))) unsigned int*)gsrc,
        (__attribute__((address_space(3))) unsigned int*)lds_dst,
        16, 0, 0);
}

// window row -> token index (shift+partition on read == reverse+unshift on write)
__device__ __forceinline__ int tok_of_winrow(int r) {
    int wid  = r / N_;
    int n    = r - wid * N_;
    int b    = wid >> 8;
    int rem  = wid & 255;
    int di   = rem >> 6;
    int hi   = (rem >> 3) & 7;
    int wi   = rem & 7;
    int wd   = n / 49;
    int rem2 = n - wd * 49;
    int wh   = rem2 / 7;
    int ww   = rem2 - wh * 7;
    int d = di * 2 + wd + 1; if (d >= D_) d -= D_;
    int h = hi * 7 + wh + 3; if (h >= H_) h -= H_;
    int w = wi * 7 + ww + 3; if (w >= W_) w -= W_;
    return ((b * D_ + d) * H_ + h) * W_ + w;
}

__device__ __forceinline__ float gelu_exact(float x) {
    return 0.5f * x * (1.0f + erff(x * 0.70710678118654752f));
}

// ---------------- LayerNorm (1 wave/row) -> bf16 out ------------------------
template<bool GATHER>
__global__ __launch_bounds__(256)
void ln_kernel(const float* __restrict__ x, const float* __restrict__ g,
               const float* __restrict__ bta, ushort* __restrict__ out, int nrows) {
    int wave = blockIdx.x * 4 + (threadIdx.x >> 6);
    int lane = threadIdx.x & 63;
    if (wave >= nrows) return;
    int srow = GATHER ? tok_of_winrow(wave) : wave;
    float4 v = ((const float4*)(x + (size_t)srow * C_))[lane];
    float s  = v.x + v.y + v.z + v.w;
    float ss = v.x*v.x + v.y*v.y + v.z*v.z + v.w*v.w;
    #pragma unroll
    for (int o = 32; o; o >>= 1) { s += __shfl_xor(s, o); ss += __shfl_xor(ss, o); }
    float mean = s * (1.0f / C_);
    float var  = ss * (1.0f / C_) - mean * mean;
    float rstd = rsqrtf(var + 1e-5f);
    float4 gg = ((const float4*)g)[lane];
    float4 bb = ((const float4*)bta)[lane];
    ushort4 o4;
    o4.x = f2b((v.x - mean) * rstd * gg.x + bb.x);
    o4.y = f2b((v.y - mean) * rstd * gg.y + bb.y);
    o4.z = f2b((v.z - mean) * rstd * gg.z + bb.z);
    o4.w = f2b((v.w - mean) * rstd * gg.w + bb.w);
    ((ushort4*)(out + (size_t)wave * C_))[lane] = o4;
}

// ---------------- rel-pos bias gather ---------------------------------------
__global__ void bias_kernel(const int* __restrict__ rel_idx,
                            const float* __restrict__ rpb,
                            float* __restrict__ biasbuf) {
    int idx = blockIdx.x * blockDim.x + threadIdx.x;
    if (idx >= NH_ * N_ * N_) return;
    int h  = idx / (N_ * N_);
    int ij = idx - h * (N_ * N_);
    biasbuf[idx] = rpb[rel_idx[ij] * NH_ + h];
}

// ---------------- fp32 -> bf16 weight convert -------------------------------
__global__ void f2b_kernel(const float* __restrict__ src, ushort* __restrict__ dst, int n) {
    int i = (blockIdx.x * blockDim.x + threadIdx.x) * 4;
    if (i >= n) return;
    float4 v = *(const float4*)(src + i);
    ushort4 o; o.x = f2b(v.x); o.y = f2b(v.y); o.z = f2b(v.z); o.w = f2b(v.w);
    *(ushort4*)(dst + i) = o;
}

// ---------------- bf16 MFMA GEMM (unchanged) --------------------------------
template<int MODE>
__global__ __launch_bounds__(256)
void gemm_bf16(const ushort* __restrict__ A, const ushort* __restrict__ Wm,
               const float* __restrict__ bias, void* __restrict__ Cout,
               const void* __restrict__ resid, int M, int K, int Nout) {
    __shared__ __align__(16) char lds[32768];
    char* ldsA = lds;
    char* ldsB = lds + 16384;
    const int tid  = threadIdx.x;
    const int wv   = tid >> 6, lane = tid & 63;
    const int m0   = blockIdx.x * 128, n0 = blockIdx.y * 128;
    const int wrow = (wv >> 1) * 64, wcol = (wv & 1) * 64;
    const int lr8  = lane >> 3, lc = lane & 7;

    f32x4 acc[4][4] = {};

    const ushort* Ag[4]; const ushort* Bg[4];
    #pragma unroll
    for (int i = 0; i < 4; ++i) {
        int row = (wv * 4 + i) * 8 + lr8;
        int gc  = lc ^ (row & 7);
        Ag[i] = A  + (size_t)(m0 + row) * K + gc * 8;
        Bg[i] = Wm + (size_t)(n0 + row) * K + gc * 8;
    }

    for (int k0 = 0; k0 < K; k0 += 64) {
        #pragma unroll
        for (int i = 0; i < 4; ++i) {
            glds16(Ag[i] + k0, ldsA + (wv * 4 + i) * 1024);
            glds16(Bg[i] + k0, ldsB + (wv * 4 + i) * 1024);
        }
        __syncthreads();
        #pragma unroll
        for (int kk = 0; kk < 2; ++kk) {
            bf16x8 af[4], bfr[4];
            #pragma unroll
            for (int i = 0; i < 4; ++i) {
                int r = wrow + i * 16 + (lane & 15);
                int c = (lane >> 4) + kk * 4;
                af[i]  = *(const bf16x8*)(ldsA + r * 128 + ((c ^ (r & 7)) * 16));
                int r2 = wcol + i * 16 + (lane & 15);
                bfr[i] = *(const bf16x8*)(ldsB + r2 * 128 + ((c ^ (r2 & 7)) * 16));
            }
            #pragma unroll
            for (int i = 0; i < 4; ++i)
                #pragma unroll
                for (int j = 0; j < 4; ++j)
                    acc[i][j] = __builtin_amdgcn_mfma_f32_16x16x32_bf16(af[i], bfr[j], acc[i][j], 0, 0, 0);
        }
        __syncthreads();
    }

    int colg[4]; float bv[4];
    #pragma unroll
    for (int j = 0; j < 4; ++j) {
        colg[j] = n0 + wcol + j * 16 + (lane & 15);
        bv[j]   = bias[colg[j]];
    }
    #pragma unroll
    for (int i = 0; i < 4; ++i) {
        #pragma unroll
        for (int r = 0; r < 4; ++r) {
            int rowg = m0 + wrow + i * 16 + ((lane >> 4) << 2) + r;
            int tok = (MODE == 1) ? tok_of_winrow(rowg) : rowg;
            #pragma unroll
            for (int j = 0; j < 4; ++j) {
                float v = acc[i][j][r] + bv[j];
                if (MODE == 0) {
                    ((ushort*)Cout)[(size_t)rowg * Nout + colg[j]] = f2b(v);
                } else if (MODE == 1) {
                    v += ((const float*)resid)[(size_t)tok * C_ + colg[j]];
                    ((float*)Cout)[(size_t)tok * C_ + colg[j]] = v;
                } else if (MODE == 2) {
                    ((ushort*)Cout)[(size_t)rowg * Nout + colg[j]] = f2b(gelu_exact(v));
                } else {
                    v += ((const float*)resid)[(size_t)rowg * Nout + colg[j]];
                    ((float*)Cout)[(size_t)rowg * Nout + colg[j]] = v;
                }
            }
        }
    }
}

// ---------------- MFMA windowed attention v2.1 ------------------------------
// Block = (window, head), 256 threads = 4 waves; mi-tiles strided across waves.
// Per-wave private Pl slice -> no barriers in the main loop. Explicit LDS
// layout via one char buffer (v2 bug: zeroing assumed Vt/Pl contiguity).
#define VT_BYTES (32 * 136 * 2)              // 8704
#define PL_BYTES (4 * 16 * 136 * 2)          // 17408
__global__ __launch_bounds__(256)
void attn_mfma(const ushort* __restrict__ qkv, const float* __restrict__ biasbuf,
               const float* __restrict__ mask, ushort* __restrict__ attn_out) {
    __shared__ __align__(16) char smem[VT_BYTES + PL_BYTES];
    ushort (*Vt)[136] = (ushort (*)[136])smem;                  // [32][136]
    ushort (*Pl)[16][136] = (ushort (*)[16][136])(smem + VT_BYTES); // [4][16][136]
    // un-swizzle: b = wid%8 + 8*hh + 64*(wid/8)
    const int b    = blockIdx.x;
    const int wid  = (b & 7) + ((b >> 6) << 3);
    const int hh   = (b >> 3) & 7;
    const int tid  = threadIdx.x;
    const int wv   = tid >> 6, lane = tid & 63;
    const int lrow = lane & 15, lgrp = lane >> 4;
    const float scale = 0.17677669529663687f;         // 1/sqrt(32)

    const ushort* base = qkv + (size_t)wid * N_ * 768 + hh * 32;
    const float* mbase = mask + (size_t)(wid & 255) * (N_ * N_);
    const float* bbase = biasbuf + (size_t)hh * (N_ * N_);
    const int rem = wid & 255;
    const bool masked = ((rem >> 6) == 3) | (((rem >> 3) & 7) == 7) | ((rem & 7) == 7);

    // zero the whole explicit LDS buffer (pads must stay 0)
    {
        uint4 z = {0, 0, 0, 0};
        uint4* l4 = (uint4*)smem;
        for (int i = tid; i < (VT_BYTES + PL_BYTES) / 16; i += 256) l4[i] = z;
    }
    __syncthreads();
    // stage V transposed: Vt[d][j] = V[j][d]
    for (int idx = tid; idx < N_ * 4; idx += 256) {
        int j = idx >> 2, dg = idx & 3;
        uint4 v = *(const uint4*)(base + (size_t)j * 768 + 512 + dg * 8);
        const ushort* pv = (const ushort*)&v;
        #pragma unroll
        for (int t = 0; t < 8; ++t) Vt[dg * 8 + t][j] = pv[t];
    }

    // K fragments direct from global (A-frag layout: row=lane&15, k=(lane>>4)*8+t)
    bf16x8 kf[7];
    #pragma unroll
    for (int nj = 0; nj < 7; ++nj) {
        int j = nj * 16 + lrow;
        kf[nj] = *(const bf16x8*)(base + (size_t)j * 768 + 256 + lgrp * 8);
    }
    __syncthreads();

    // V fragments from Vt (B-frag: lane holds V[kt*32+lgrp*8+t][dt*16+lrow])
    bf16x8 vf[2][4];
    #pragma unroll
    for (int dt = 0; dt < 2; ++dt)
        #pragma unroll
        for (int kt = 0; kt < 4; ++kt)
            vf[dt][kt] = *(const bf16x8*)(&Vt[dt * 16 + lrow][kt * 32 + lgrp * 8]);

    for (int mi = wv; mi < 7; mi += 4) {
        const int ibase = mi * 16;
        bf16x8 qf = *(const bf16x8*)(base + (size_t)(ibase + lrow) * 768 + lgrp * 8);

        f32x4 s[7];
        #pragma unroll
        for (int nj = 0; nj < 7; ++nj) {
            f32x4 z = {0.f, 0.f, 0.f, 0.f};
            s[nj] = __builtin_amdgcn_mfma_f32_16x16x32_bf16(qf, kf[nj], z, 0, 0, 0);
        }

        // scale + bias (+mask) in C-layout: row = ibase+lgrp*4+r, col = nj*16+lrow
        #pragma unroll
        for (int nj = 0; nj < 7; ++nj) {
            int j = nj * 16 + lrow;
            #pragma unroll
            for (int r = 0; r < 4; ++r) {
                int i = ibase + lgrp * 4 + r;
                if (j < N_ && i < N_) {
                    float t = s[nj][r] * scale + bbase[i * N_ + j];
                    if (masked) t += mbase[i * N_ + j];
                    s[nj][r] = t;
                } else {
                    s[nj][r] = -1e30f;
                }
            }
        }

        // full softmax: reduce over nj (regs) then the 16 lanes of the col group
        float rinv[4];
        #pragma unroll
        for (int r = 0; r < 4; ++r) {
            float m = s[0][r];
            #pragma unroll
            for (int nj = 1; nj < 7; ++nj) m = fmaxf(m, s[nj][r]);
            #pragma unroll
            for (int o = 1; o < 16; o <<= 1) m = fmaxf(m, __shfl_xor(m, o));
            float acc = 0.f;
            #pragma unroll
            for (int nj = 0; nj < 7; ++nj) {
                float p = __expf(s[nj][r] - m);
                s[nj][r] = p;
                acc += p;
            }
            #pragma unroll
            for (int o = 1; o < 16; o <<= 1) acc += __shfl_xor(acc, o);
            rinv[r] = 1.f / acc;
        }

        // P tile to this wave's private LDS slice (no block barrier needed)
        #pragma unroll
        for (int nj = 0; nj < 7; ++nj)
            #pragma unroll
            for (int r = 0; r < 4; ++r)
                Pl[wv][lgrp * 4 + r][nj * 16 + lrow] = f2b(s[nj][r] * rinv[r]);

        // PV: O[i][d] = sum_j P[i][j] V[j][d]
        f32x4 o0 = {0.f, 0.f, 0.f, 0.f}, o1 = {0.f, 0.f, 0.f, 0.f};
        #pragma unroll
        for (int kt = 0; kt < 4; ++kt) {
            bf16x8 pf = *(const bf16x8*)(&Pl[wv][lrow][kt * 32 + lgrp * 8]);
            o0 = __builtin_amdgcn_mfma_f32_16x16x32_bf16(pf, vf[0][kt], o0, 0, 0, 0);
            o1 = __builtin_amdgcn_mfma_f32_16x16x32_bf16(pf, vf[1][kt], o1, 0, 0, 0);
        }

        #pragma unroll
        for (int r = 0; r < 4; ++r) {
            int i = ibase + lgrp * 4 + r;
            if (i < N_) {
                size_t rb = ((size_t)(wid * N_ + i)) * C_ + hh * 32;
                attn_out[rb + lrow]      = f2b(o0[r]);
                attn_out[rb + 16 + lrow] = f2b(o1[r]);
            }
        }
    }
}

// ---------------------------------------------------------------------------
extern "C" void kernel_launch(void* const* d_in, const int* in_sizes, int n_in,
                              void* d_out, int out_size, void* d_ws, size_t ws_size,
                              hipStream_t stream) {
    const float* x      = (const float*)d_in[0];
    const float* qkv_w  = (const float*)d_in[1];
    const float* qkv_b  = (const float*)d_in[2];
    const float* proj_w = (const float*)d_in[3];
    const float* proj_b = (const float*)d_in[4];
    const float* rpb    = (const float*)d_in[5];
    const float* ln1_g  = (const float*)d_in[6];
    const float* ln1_b  = (const float*)d_in[7];
    const float* ln2_g  = (const float*)d_in[8];
    const float* ln2_b  = (const float*)d_in[9];
    const float* fc1_w  = (const float*)d_in[10];
    const float* fc1_b  = (const float*)d_in[11];
    const float* fc2_w  = (const float*)d_in[12];
    const float* fc2_b  = (const float*)d_in[13];
    const int*   rel_idx= (const int*)d_in[14];
    const float* mask   = (const float*)d_in[15];
    float* out = (float*)d_out;

    char* ws = (char*)d_ws;
    ushort* regionA = (ushort*)ws;                                   // qkv/hidden bf16
    ushort* regionB = (ushort*)(ws + (size_t)TOK * HID * 2);         // win/attn_out/h2 bf16
    ushort* wq  = (ushort*)(ws + (size_t)TOK * HID * 2 + (size_t)TOK * C_ * 2);
    ushort* wp  = wq + 768 * 256;
    ushort* w1  = wp + 256 * 256;
    ushort* w2  = w1 + HID * 256;
    float* biasbuf = (float*)(w2 + 256 * HID);

    // K0: rel-pos bias gather + weight converts
    bias_kernel<<<(NH_ * N_ * N_ + 255) / 256, 256, 0, stream>>>(rel_idx, rpb, biasbuf);
    f2b_kernel<<<(768 * 256 / 4 + 255) / 256, 256, 0, stream>>>(qkv_w, wq, 768 * 256);
    f2b_kernel<<<(256 * 256 / 4 + 255) / 256, 256, 0, stream>>>(proj_w, wp, 256 * 256);
    f2b_kernel<<<(HID * 256 / 4 + 255) / 256, 256, 0, stream>>>(fc1_w, w1, HID * 256);
    f2b_kernel<<<(256 * HID / 4 + 255) / 256, 256, 0, stream>>>(fc2_w, w2, 256 * HID);

    // K1: LN1 + shift + window partition -> regionB bf16
    ln_kernel<true><<<TOK / 4, 256, 0, stream>>>(x, ln1_g, ln1_b, regionB, TOK);

    // K2: QKV GEMM -> regionA bf16 (50176 x 768)
    {
        dim3 g(TOK / 128, 768 / 128);
        gemm_bf16<0><<<g, 256, 0, stream>>>(regionB, wq, qkv_b, regionA, nullptr, TOK, 256, 768);
    }

    // K3: MFMA windowed attention -> regionB bf16
    attn_mfma<<<NWIN_TOT * NH_, 256, 0, stream>>>(regionA, biasbuf, mask, regionB);

    // K4: proj GEMM + window reverse + unshift + residual(x) -> out fp32
    {
        dim3 g(TOK / 128, 256 / 128);
        gemm_bf16<1><<<g, 256, 0, stream>>>(regionB, wp, proj_b, out, x, TOK, 256, 256);
    }

    // K5: LN2 -> regionB bf16
    ln_kernel<false><<<TOK / 4, 256, 0, stream>>>(out, ln2_g, ln2_b, regionB, TOK);

    // K6: fc1 + GELU -> regionA bf16 (50176 x 1024)
    {
        dim3 g(TOK / 128, HID / 128);
        gemm_bf16<2><<<g, 256, 0, stream>>>(regionB, w1, fc1_b, regionA, nullptr, TOK, 256, HID);
    }

    // K7: fc2 + residual (in place on out)
    {
        dim3 g(TOK / 128, 256 / 128);
        gemm_bf16<3><<<g, 256, 0, stream>>>(regionA, w2, fc2_b, out, out, TOK, HID, 256);
    }
}

// Round 6
// 293.287 us; speedup vs baseline: 1.2593x; 1.2593x over previous
//
#include <hip/hip_runtime.h>
#include <hip/hip_bf16.h>
#include <math.h>

#define B_  2
#define D_  8
#define H_  56
#define W_  56
#define C_  256
#define NH_ 8
#define HD_ 32
#define N_  98
#define NWIN_TOT 512
#define TOK (B_*D_*H_*W_)   // 50176
#define HID 1024

typedef short bf16x8 __attribute__((ext_vector_type(8)));
typedef float f32x4  __attribute__((ext_vector_type(4)));

__device__ __forceinline__ ushort f2b(float f) {
    union { float f; unsigned u; } v; v.f = f;
    unsigned r = v.u + 0x7fff + ((v.u >> 16) & 1);
    return (ushort)(r >> 16);
}
__device__ __forceinline__ float b2f(ushort h) {
    union { unsigned u; float f; } v; v.u = ((unsigned)h) << 16;
    return v.f;
}

__device__ __forceinline__ void glds16(const void* gsrc, void* lds_dst) {
    __builtin_amdgcn_global_load_lds(
        (const __attribute__((address_space(1))) unsigned int*)gsrc,
        (__attribute__((address_space(3))) unsigned int*)lds_dst,
        16, 0, 0);
}

// window row -> token index (shift+partition on read == reverse+unshift on write)
__device__ __forceinline__ int tok_of_winrow(int r) {
    int wid  = r / N_;
    int n    = r - wid * N_;
    int b    = wid >> 8;
    int rem  = wid & 255;
    int di   = rem >> 6;
    int hi   = (rem >> 3) & 7;
    int wi   = rem & 7;
    int wd   = n / 49;
    int rem2 = n - wd * 49;
    int wh   = rem2 / 7;
    int ww   = rem2 - wh * 7;
    int d = di * 2 + wd + 1; if (d >= D_) d -= D_;
    int h = hi * 7 + wh + 3; if (h >= H_) h -= H_;
    int w = wi * 7 + ww + 3; if (w >= W_) w -= W_;
    return ((b * D_ + d) * H_ + h) * W_ + w;
}

__device__ __forceinline__ float gelu_exact(float x) {
    return 0.5f * x * (1.0f + erff(x * 0.70710678118654752f));
}

// ---------------- LayerNorm (1 wave/row) -> bf16 out ------------------------
template<bool GATHER>
__global__ __launch_bounds__(256)
void ln_kernel(const float* __restrict__ x, const float* __restrict__ g,
               const float* __restrict__ bta, ushort* __restrict__ out, int nrows) {
    int wave = blockIdx.x * 4 + (threadIdx.x >> 6);
    int lane = threadIdx.x & 63;
    if (wave >= nrows) return;
    int srow = GATHER ? tok_of_winrow(wave) : wave;
    float4 v = ((const float4*)(x + (size_t)srow * C_))[lane];
    float s  = v.x + v.y + v.z + v.w;
    float ss = v.x*v.x + v.y*v.y + v.z*v.z + v.w*v.w;
    #pragma unroll
    for (int o = 32; o; o >>= 1) { s += __shfl_xor(s, o); ss += __shfl_xor(ss, o); }
    float mean = s * (1.0f / C_);
    float var  = ss * (1.0f / C_) - mean * mean;
    float rstd = rsqrtf(var + 1e-5f);
    float4 gg = ((const float4*)g)[lane];
    float4 bb = ((const float4*)bta)[lane];
    ushort4 o4;
    o4.x = f2b((v.x - mean) * rstd * gg.x + bb.x);
    o4.y = f2b((v.y - mean) * rstd * gg.y + bb.y);
    o4.z = f2b((v.z - mean) * rstd * gg.z + bb.z);
    o4.w = f2b((v.w - mean) * rstd * gg.w + bb.w);
    ((ushort4*)(out + (size_t)wave * C_))[lane] = o4;
}

// ---------------- combined (bias+mask) bf16 table ---------------------------
// Tb[p*8+hh][i][j] = rel-pos-bias[hh][i][j] + mask_pattern[p][i][j]
// p = (di==3) | (hi==7)<<1 | (wi==7)<<2 ; representative window rem = di*64+hi*8+wi
__global__ void tbl_kernel(const int* __restrict__ rel_idx,
                           const float* __restrict__ rpb,
                           const float* __restrict__ mask,
                           ushort* __restrict__ Tb) {
    int idx = blockIdx.x * blockDim.x + threadIdx.x;
    if (idx >= 64 * N_ * N_) return;
    int ph = idx / (N_ * N_);
    int ij = idx - ph * (N_ * N_);
    int p = ph >> 3, hh = ph & 7;
    int di = (p & 1) ? 3 : 0, hi = (p & 2) ? 7 : 0, wi = (p & 4) ? 7 : 0;
    int rep = di * 64 + hi * 8 + wi;
    float b = rpb[rel_idx[ij] * NH_ + hh];
    float m = mask[(size_t)rep * (N_ * N_) + ij];
    Tb[(size_t)ph * (N_ * N_) + ij] = f2b(b + m);
}

// ---------------- fp32 -> bf16 weight convert -------------------------------
__global__ void f2b_kernel(const float* __restrict__ src, ushort* __restrict__ dst, int n) {
    int i = (blockIdx.x * blockDim.x + threadIdx.x) * 4;
    if (i >= n) return;
    float4 v = *(const float4*)(src + i);
    ushort4 o; o.x = f2b(v.x); o.y = f2b(v.y); o.z = f2b(v.z); o.w = f2b(v.w);
    *(ushort4*)(dst + i) = o;
}

// ---------------- bf16 MFMA GEMM (unchanged) --------------------------------
template<int MODE>
__global__ __launch_bounds__(256)
void gemm_bf16(const ushort* __restrict__ A, const ushort* __restrict__ Wm,
               const float* __restrict__ bias, void* __restrict__ Cout,
               const void* __restrict__ resid, int M, int K, int Nout) {
    __shared__ __align__(16) char lds[32768];
    char* ldsA = lds;
    char* ldsB = lds + 16384;
    const int tid  = threadIdx.x;
    const int wv   = tid >> 6, lane = tid & 63;
    const int m0   = blockIdx.x * 128, n0 = blockIdx.y * 128;
    const int wrow = (wv >> 1) * 64, wcol = (wv & 1) * 64;
    const int lr8  = lane >> 3, lc = lane & 7;

    f32x4 acc[4][4] = {};

    const ushort* Ag[4]; const ushort* Bg[4];
    #pragma unroll
    for (int i = 0; i < 4; ++i) {
        int row = (wv * 4 + i) * 8 + lr8;
        int gc  = lc ^ (row & 7);
        Ag[i] = A  + (size_t)(m0 + row) * K + gc * 8;
        Bg[i] = Wm + (size_t)(n0 + row) * K + gc * 8;
    }

    for (int k0 = 0; k0 < K; k0 += 64) {
        #pragma unroll
        for (int i = 0; i < 4; ++i) {
            glds16(Ag[i] + k0, ldsA + (wv * 4 + i) * 1024);
            glds16(Bg[i] + k0, ldsB + (wv * 4 + i) * 1024);
        }
        __syncthreads();
        #pragma unroll
        for (int kk = 0; kk < 2; ++kk) {
            bf16x8 af[4], bfr[4];
            #pragma unroll
            for (int i = 0; i < 4; ++i) {
                int r = wrow + i * 16 + (lane & 15);
                int c = (lane >> 4) + kk * 4;
                af[i]  = *(const bf16x8*)(ldsA + r * 128 + ((c ^ (r & 7)) * 16));
                int r2 = wcol + i * 16 + (lane & 15);
                bfr[i] = *(const bf16x8*)(ldsB + r2 * 128 + ((c ^ (r2 & 7)) * 16));
            }
            #pragma unroll
            for (int i = 0; i < 4; ++i)
                #pragma unroll
                for (int j = 0; j < 4; ++j)
                    acc[i][j] = __builtin_amdgcn_mfma_f32_16x16x32_bf16(af[i], bfr[j], acc[i][j], 0, 0, 0);
        }
        __syncthreads();
    }

    int colg[4]; float bv[4];
    #pragma unroll
    for (int j = 0; j < 4; ++j) {
        colg[j] = n0 + wcol + j * 16 + (lane & 15);
        bv[j]   = bias[colg[j]];
    }
    #pragma unroll
    for (int i = 0; i < 4; ++i) {
        #pragma unroll
        for (int r = 0; r < 4; ++r) {
            int rowg = m0 + wrow + i * 16 + ((lane >> 4) << 2) + r;
            int tok = (MODE == 1) ? tok_of_winrow(rowg) : rowg;
            #pragma unroll
            for (int j = 0; j < 4; ++j) {
                float v = acc[i][j][r] + bv[j];
                if (MODE == 0) {
                    ((ushort*)Cout)[(size_t)rowg * Nout + colg[j]] = f2b(v);
                } else if (MODE == 1) {
                    v += ((const float*)resid)[(size_t)tok * C_ + colg[j]];
                    ((float*)Cout)[(size_t)tok * C_ + colg[j]] = v;
                } else if (MODE == 2) {
                    ((ushort*)Cout)[(size_t)rowg * Nout + colg[j]] = f2b(gelu_exact(v));
                } else {
                    v += ((const float*)resid)[(size_t)rowg * Nout + colg[j]];
                    ((float*)Cout)[(size_t)rowg * Nout + colg[j]] = v;
                }
            }
        }
    }
}

// ---------------- MFMA windowed attention v3 --------------------------------
// Block = (window, head), 4 waves, mi-tiles strided across waves.
// Q,K,V staged into LDS via global_load_lds (coalesced, 16B, source-swizzled);
// V B-frags assembled one-time via scalar LDS reads; bias+mask fused bf16
// table; no max-reduce (inputs bounded); barrier-free main loop.
#define QOFF 0
#define KOFF 7168
#define VOFF 14336      // 128 rows x 64B (rows >=112 stay zero)
#define POFF 22528      // Pl[4][16][136] ushort
#define SMEM_BYTES 39936
__global__ __launch_bounds__(256)
void attn_mfma(const ushort* __restrict__ qkv, const ushort* __restrict__ Tb,
               ushort* __restrict__ attn_out) {
    __shared__ __align__(16) char smem[SMEM_BYTES];
    ushort (*Pl)[16][136] = (ushort (*)[16][136])(smem + POFF);
    // un-swizzle: b = wid%8 + 8*hh + 64*(wid/8)  (heads of a window share XCD)
    const int b    = blockIdx.x;
    const int wid  = (b & 7) + ((b >> 6) << 3);
    const int hh   = (b >> 3) & 7;
    const int tid  = threadIdx.x;
    const int wv   = tid >> 6, lane = tid & 63;
    const int lrow = lane & 15, lgrp = lane >> 4;
    const float scale = 0.17677669529663687f;     // 1/sqrt(32)

    const ushort* base = qkv + (size_t)wid * N_ * 768 + hh * 32;
    const int rem = wid & 255;
    const int pat = (((rem >> 6) == 3) ? 1 : 0) | ((((rem >> 3) & 7) == 7) ? 2 : 0)
                  | (((rem & 7) == 7) ? 4 : 0);
    const ushort* tb = Tb + (size_t)(pat * 8 + hh) * (N_ * N_);

    // zero V pad rows + Pl (everything from byte 21504 up)
    {
        uint4 z = {0, 0, 0, 0};
        uint4* l4 = (uint4*)(smem + 21504);
        for (int i = tid; i < (SMEM_BYTES - 21504) / 16; i += 256) l4[i] = z;
    }
    __syncthreads();

    // stage Q,K,V: rows padded to 112 (clamped to row 97), 64B/row,
    // source chunk pre-swizzled with (row&3) so LDS stays linear.
    #pragma unroll
    for (int sect = 0; sect < 3; ++sect) {
        char* dstbase = smem + sect * 7168;
        const ushort* src = base + sect * 256;
        for (int c0 = wv * 64; c0 < 448; c0 += 256) {
            int c = c0 + lane;
            int r = c >> 2; if (r > 97) r = 97;
            int cc = c & 3;
            glds16(src + (size_t)r * 768 + ((cc ^ (r & 3)) * 8), dstbase + c0 * 16);
        }
    }
    __syncthreads();   // drains vmcnt before barrier

    const int swz = (lgrp ^ (lrow & 3)) << 4;   // 16B-chunk swizzle for Q/K reads

    // K fragments from LDS (A-frag layout: row=lrow, k-chunk=lgrp)
    bf16x8 kf[7];
    #pragma unroll
    for (int nj = 0; nj < 7; ++nj)
        kf[nj] = *(const bf16x8*)(smem + KOFF + (nj * 16 + lrow) * 64 + swz);

    // V B-frags: lane holds V[kt*32+lgrp*8+t][dt*16+lrow], scalar reads (one-time)
    bf16x8 vf[2][4];
    #pragma unroll
    for (int dt = 0; dt < 2; ++dt)
        #pragma unroll
        for (int kt = 0; kt < 4; ++kt) {
            bf16x8 tmp;
            #pragma unroll
            for (int t = 0; t < 8; ++t) {
                int R = kt * 32 + lgrp * 8 + t;
                int q = dt * 2 + (lrow >> 3);
                tmp[t] = *(const short*)(smem + VOFF + R * 64 +
                                         ((q ^ (t & 3)) << 4) + ((lrow & 7) << 1));
            }
            vf[dt][kt] = tmp;
        }

    for (int mi = wv; mi < 7; mi += 4) {
        const int ibase = mi * 16;
        bf16x8 qf = *(const bf16x8*)(smem + QOFF + (ibase + lrow) * 64 + swz);

        f32x4 s[7];
        #pragma unroll
        for (int nj = 0; nj < 7; ++nj) {
            f32x4 z = {0.f, 0.f, 0.f, 0.f};
            s[nj] = __builtin_amdgcn_mfma_f32_16x16x32_bf16(qf, kf[nj], z, 0, 0, 0);
        }

        // scale + fused bias/mask; exp without max (inputs bounded)
        #pragma unroll
        for (int nj = 0; nj < 7; ++nj) {
            int j = nj * 16 + lrow;
            #pragma unroll
            for (int r = 0; r < 4; ++r) {
                int i = ibase + lgrp * 4 + r;
                s[nj][r] = (j < N_ && i < N_)
                    ? s[nj][r] * scale + b2f(tb[i * N_ + j]) : -1e30f;
            }
        }

        float rinv[4];
        #pragma unroll
        for (int r = 0; r < 4; ++r) {
            float acc = 0.f;
            #pragma unroll
            for (int nj = 0; nj < 7; ++nj) {
                float p = __expf(s[nj][r]);
                s[nj][r] = p;
                acc += p;
            }
            #pragma unroll
            for (int o = 1; o < 16; o <<= 1) acc += __shfl_xor(acc, o);
            rinv[r] = 1.f / acc;
        }

        // P tile to this wave's private LDS slice (cols >=112 stay zero)
        #pragma unroll
        for (int nj = 0; nj < 7; ++nj)
            #pragma unroll
            for (int r = 0; r < 4; ++r)
                Pl[wv][lgrp * 4 + r][nj * 16 + lrow] = f2b(s[nj][r] * rinv[r]);

        // PV: O[i][d] = sum_j P[i][j] V[j][d]
        f32x4 o0 = {0.f, 0.f, 0.f, 0.f}, o1 = {0.f, 0.f, 0.f, 0.f};
        #pragma unroll
        for (int kt = 0; kt < 4; ++kt) {
            bf16x8 pf = *(const bf16x8*)(&Pl[wv][lrow][kt * 32 + lgrp * 8]);
            o0 = __builtin_amdgcn_mfma_f32_16x16x32_bf16(pf, vf[0][kt], o0, 0, 0, 0);
            o1 = __builtin_amdgcn_mfma_f32_16x16x32_bf16(pf, vf[1][kt], o1, 0, 0, 0);
        }

        #pragma unroll
        for (int r = 0; r < 4; ++r) {
            int i = ibase + lgrp * 4 + r;
            if (i < N_) {
                size_t rb = ((size_t)(wid * N_ + i)) * C_ + hh * 32;
                attn_out[rb + lrow]      = f2b(o0[r]);
                attn_out[rb + 16 + lrow] = f2b(o1[r]);
            }
        }
    }
}

// ---------------------------------------------------------------------------
extern "C" void kernel_launch(void* const* d_in, const int* in_sizes, int n_in,
                              void* d_out, int out_size, void* d_ws, size_t ws_size,
                              hipStream_t stream) {
    const float* x      = (const float*)d_in[0];
    const float* qkv_w  = (const float*)d_in[1];
    const float* qkv_b  = (const float*)d_in[2];
    const float* proj_w = (const float*)d_in[3];
    const float* proj_b = (const float*)d_in[4];
    const float* rpb    = (const float*)d_in[5];
    const float* ln1_g  = (const float*)d_in[6];
    const float* ln1_b  = (const float*)d_in[7];
    const float* ln2_g  = (const float*)d_in[8];
    const float* ln2_b  = (const float*)d_in[9];
    const float* fc1_w  = (const float*)d_in[10];
    const float* fc1_b  = (const float*)d_in[11];
    const float* fc2_w  = (const float*)d_in[12];
    const float* fc2_b  = (const float*)d_in[13];
    const int*   rel_idx= (const int*)d_in[14];
    const float* mask   = (const float*)d_in[15];
    float* out = (float*)d_out;

    char* ws = (char*)d_ws;
    ushort* regionA = (ushort*)ws;                                   // qkv/hidden bf16
    ushort* regionB = (ushort*)(ws + (size_t)TOK * HID * 2);         // win/attn_out/h2 bf16
    ushort* wq  = (ushort*)(ws + (size_t)TOK * HID * 2 + (size_t)TOK * C_ * 2);
    ushort* wp  = wq + 768 * 256;
    ushort* w1  = wp + 256 * 256;
    ushort* w2  = w1 + HID * 256;
    ushort* Tb  = w2 + 256 * HID;                                    // 64 x 98 x 98 bf16

    // K0: combined bias+mask table + weight converts
    tbl_kernel<<<(64 * N_ * N_ + 255) / 256, 256, 0, stream>>>(rel_idx, rpb, mask, Tb);
    f2b_kernel<<<(768 * 256 / 4 + 255) / 256, 256, 0, stream>>>(qkv_w, wq, 768 * 256);
    f2b_kernel<<<(256 * 256 / 4 + 255) / 256, 256, 0, stream>>>(proj_w, wp, 256 * 256);
    f2b_kernel<<<(HID * 256 / 4 + 255) / 256, 256, 0, stream>>>(fc1_w, w1, HID * 256);
    f2b_kernel<<<(256 * HID / 4 + 255) / 256, 256, 0, stream>>>(fc2_w, w2, 256 * HID);

    // K1: LN1 + shift + window partition -> regionB bf16
    ln_kernel<true><<<TOK / 4, 256, 0, stream>>>(x, ln1_g, ln1_b, regionB, TOK);

    // K2: QKV GEMM -> regionA bf16 (50176 x 768)
    {
        dim3 g(TOK / 128, 768 / 128);
        gemm_bf16<0><<<g, 256, 0, stream>>>(regionB, wq, qkv_b, regionA, nullptr, TOK, 256, 768);
    }

    // K3: MFMA windowed attention -> regionB bf16
    attn_mfma<<<NWIN_TOT * NH_, 256, 0, stream>>>(regionA, Tb, regionB);

    // K4: proj GEMM + window reverse + unshift + residual(x) -> out fp32
    {
        dim3 g(TOK / 128, 256 / 128);
        gemm_bf16<1><<<g, 256, 0, stream>>>(regionB, wp, proj_b, out, x, TOK, 256, 256);
    }

    // K5: LN2 -> regionB bf16
    ln_kernel<false><<<TOK / 4, 256, 0, stream>>>(out, ln2_g, ln2_b, regionB, TOK);

    // K6: fc1 + GELU -> regionA bf16 (50176 x 1024)
    {
        dim3 g(TOK / 128, HID / 128);
        gemm_bf16<2><<<g, 256, 0, stream>>>(regionB, w1, fc1_b, regionA, nullptr, TOK, 256, HID);
    }

    // K7: fc2 + residual (in place on out)
    {
        dim3 g(TOK / 128, 256 / 128);
        gemm_bf16<3><<<g, 256, 0, stream>>>(regionA, w2, fc2_b, out, out, TOK, HID, 256);
    }
}

// Round 7
// 258.106 us; speedup vs baseline: 1.4309x; 1.1363x over previous
//
#include <hip/hip_runtime.h>
#include <hip/hip_bf16.h>
#include <math.h>

#define B_  2
#define D_  8
#define H_  56
#define W_  56
#define C_  256
#define NH_ 8
#define HD_ 32
#define N_  98
#define NWIN_TOT 512
#define TOK (B_*D_*H_*W_)   // 50176
#define HID 1024

typedef short bf16x8 __attribute__((ext_vector_type(8)));
typedef float f32x4  __attribute__((ext_vector_type(4)));

__device__ __forceinline__ ushort f2b(float f) {
    union { float f; unsigned u; } v; v.f = f;
    unsigned r = v.u + 0x7fff + ((v.u >> 16) & 1);
    return (ushort)(r >> 16);
}
__device__ __forceinline__ float b2f(ushort h) {
    union { unsigned u; float f; } v; v.u = ((unsigned)h) << 16;
    return v.f;
}

__device__ __forceinline__ void glds16(const void* gsrc, void* lds_dst) {
    __builtin_amdgcn_global_load_lds(
        (const __attribute__((address_space(1))) unsigned int*)gsrc,
        (__attribute__((address_space(3))) unsigned int*)lds_dst,
        16, 0, 0);
}

// window row -> token index (shift+partition on read == reverse+unshift on write)
__device__ __forceinline__ int tok_of_winrow(int r) {
    int wid  = r / N_;
    int n    = r - wid * N_;
    int b    = wid >> 8;
    int rem  = wid & 255;
    int di   = rem >> 6;
    int hi   = (rem >> 3) & 7;
    int wi   = rem & 7;
    int wd   = n / 49;
    int rem2 = n - wd * 49;
    int wh   = rem2 / 7;
    int ww   = rem2 - wh * 7;
    int d = di * 2 + wd + 1; if (d >= D_) d -= D_;
    int h = hi * 7 + wh + 3; if (h >= H_) h -= H_;
    int w = wi * 7 + ww + 3; if (w >= W_) w -= W_;
    return ((b * D_ + d) * H_ + h) * W_ + w;
}

__device__ __forceinline__ float gelu_exact(float x) {
    return 0.5f * x * (1.0f + erff(x * 0.70710678118654752f));
}

// ---------------- LayerNorm (1 wave/row) -> bf16 out ------------------------
template<bool GATHER>
__global__ __launch_bounds__(256)
void ln_kernel(const float* __restrict__ x, const float* __restrict__ g,
               const float* __restrict__ bta, ushort* __restrict__ out, int nrows) {
    int wave = blockIdx.x * 4 + (threadIdx.x >> 6);
    int lane = threadIdx.x & 63;
    if (wave >= nrows) return;
    int srow = GATHER ? tok_of_winrow(wave) : wave;
    float4 v = ((const float4*)(x + (size_t)srow * C_))[lane];
    float s  = v.x + v.y + v.z + v.w;
    float ss = v.x*v.x + v.y*v.y + v.z*v.z + v.w*v.w;
    #pragma unroll
    for (int o = 32; o; o >>= 1) { s += __shfl_xor(s, o); ss += __shfl_xor(ss, o); }
    float mean = s * (1.0f / C_);
    float var  = ss * (1.0f / C_) - mean * mean;
    float rstd = rsqrtf(var + 1e-5f);
    float4 gg = ((const float4*)g)[lane];
    float4 bb = ((const float4*)bta)[lane];
    ushort4 o4;
    o4.x = f2b((v.x - mean) * rstd * gg.x + bb.x);
    o4.y = f2b((v.y - mean) * rstd * gg.y + bb.y);
    o4.z = f2b((v.z - mean) * rstd * gg.z + bb.z);
    o4.w = f2b((v.w - mean) * rstd * gg.w + bb.w);
    ((ushort4*)(out + (size_t)wave * C_))[lane] = o4;
}

// ---------------- MFMA-layout combined (bias+mask) table --------------------
// Tb2[((pat*8+hh)*7+mi)*14 + nj*2+q][lane]: u32 = bf16(T[i0][j]) | bf16(T[i0+1][j])<<16
// i0 = mi*16 + lgrp*4 + 2q, j = nj*16 + lrow; OOB entries baked to -1e30.
#define TB2_WORDS (8 * 8 * 7 * 14 * 64)   // 401408
__global__ void tbl_kernel(const int* __restrict__ rel_idx,
                           const float* __restrict__ rpb,
                           const float* __restrict__ mask,
                           uint* __restrict__ Tb2) {
    int idx = blockIdx.x * blockDim.x + threadIdx.x;
    if (idx >= TB2_WORDS) return;
    int lane = idx & 63;
    int t    = idx >> 6;
    int nq   = t % 14;  int t2 = t / 14;
    int mi   = t2 % 7;  int ph = t2 / 7;
    int pat  = ph >> 3, hh = ph & 7;
    int nj   = nq >> 1, q = nq & 1;
    int lrow = lane & 15, lgrp = lane >> 4;
    int j  = nj * 16 + lrow;
    int i0 = mi * 16 + lgrp * 4 + q * 2;
    int di = (pat & 1) ? 3 : 0, hi = (pat & 2) ? 7 : 0, wi = (pat & 4) ? 7 : 0;
    int rep = di * 64 + hi * 8 + wi;
    float lo = -1e30f, hv = -1e30f;
    if (j < N_) {
        if (i0 < N_)
            lo = rpb[rel_idx[i0 * N_ + j] * NH_ + hh] + mask[(size_t)rep * (N_*N_) + i0 * N_ + j];
        if (i0 + 1 < N_)
            hv = rpb[rel_idx[(i0+1) * N_ + j] * NH_ + hh] + mask[(size_t)rep * (N_*N_) + (i0+1) * N_ + j];
    }
    Tb2[idx] = (uint)f2b(lo) | ((uint)f2b(hv) << 16);
}

// ---------------- fp32 -> bf16 weight convert (4 fused) ---------------------
__global__ void f2b4_kernel(const float* __restrict__ s0, ushort* __restrict__ d0, int n0,
                            const float* __restrict__ s1, ushort* __restrict__ d1, int n1,
                            const float* __restrict__ s2, ushort* __restrict__ d2, int n2,
                            const float* __restrict__ s3, ushort* __restrict__ d3, int n3) {
    const float* s; ushort* d; int n;
    switch (blockIdx.y) {
        case 0: s = s0; d = d0; n = n0; break;
        case 1: s = s1; d = d1; n = n1; break;
        case 2: s = s2; d = d2; n = n2; break;
        default: s = s3; d = d3; n = n3; break;
    }
    int i = (blockIdx.x * blockDim.x + threadIdx.x) * 4;
    if (i >= n) return;
    float4 v = *(const float4*)(s + i);
    ushort4 o; o.x = f2b(v.x); o.y = f2b(v.y); o.z = f2b(v.z); o.w = f2b(v.w);
    *(ushort4*)(d + i) = o;
}

// ---------------- bf16 MFMA GEMM (unchanged) --------------------------------
template<int MODE>
__global__ __launch_bounds__(256)
void gemm_bf16(const ushort* __restrict__ A, const ushort* __restrict__ Wm,
               const float* __restrict__ bias, void* __restrict__ Cout,
               const void* __restrict__ resid, int M, int K, int Nout) {
    __shared__ __align__(16) char lds[32768];
    char* ldsA = lds;
    char* ldsB = lds + 16384;
    const int tid  = threadIdx.x;
    const int wv   = tid >> 6, lane = tid & 63;
    const int m0   = blockIdx.x * 128, n0 = blockIdx.y * 128;
    const int wrow = (wv >> 1) * 64, wcol = (wv & 1) * 64;
    const int lr8  = lane >> 3, lc = lane & 7;

    f32x4 acc[4][4] = {};

    const ushort* Ag[4]; const ushort* Bg[4];
    #pragma unroll
    for (int i = 0; i < 4; ++i) {
        int row = (wv * 4 + i) * 8 + lr8;
        int gc  = lc ^ (row & 7);
        Ag[i] = A  + (size_t)(m0 + row) * K + gc * 8;
        Bg[i] = Wm + (size_t)(n0 + row) * K + gc * 8;
    }

    for (int k0 = 0; k0 < K; k0 += 64) {
        #pragma unroll
        for (int i = 0; i < 4; ++i) {
            glds16(Ag[i] + k0, ldsA + (wv * 4 + i) * 1024);
            glds16(Bg[i] + k0, ldsB + (wv * 4 + i) * 1024);
        }
        __syncthreads();
        #pragma unroll
        for (int kk = 0; kk < 2; ++kk) {
            bf16x8 af[4], bfr[4];
            #pragma unroll
            for (int i = 0; i < 4; ++i) {
                int r = wrow + i * 16 + (lane & 15);
                int c = (lane >> 4) + kk * 4;
                af[i]  = *(const bf16x8*)(ldsA + r * 128 + ((c ^ (r & 7)) * 16));
                int r2 = wcol + i * 16 + (lane & 15);
                bfr[i] = *(const bf16x8*)(ldsB + r2 * 128 + ((c ^ (r2 & 7)) * 16));
            }
            #pragma unroll
            for (int i = 0; i < 4; ++i)
                #pragma unroll
                for (int j = 0; j < 4; ++j)
                    acc[i][j] = __builtin_amdgcn_mfma_f32_16x16x32_bf16(af[i], bfr[j], acc[i][j], 0, 0, 0);
        }
        __syncthreads();
    }

    int colg[4]; float bv[4];
    #pragma unroll
    for (int j = 0; j < 4; ++j) {
        colg[j] = n0 + wcol + j * 16 + (lane & 15);
        bv[j]   = bias[colg[j]];
    }
    #pragma unroll
    for (int i = 0; i < 4; ++i) {
        #pragma unroll
        for (int r = 0; r < 4; ++r) {
            int rowg = m0 + wrow + i * 16 + ((lane >> 4) << 2) + r;
            int tok = (MODE == 1) ? tok_of_winrow(rowg) : rowg;
            #pragma unroll
            for (int j = 0; j < 4; ++j) {
                float v = acc[i][j][r] + bv[j];
                if (MODE == 0) {
                    ((ushort*)Cout)[(size_t)rowg * Nout + colg[j]] = f2b(v);
                } else if (MODE == 1) {
                    v += ((const float*)resid)[(size_t)tok * C_ + colg[j]];
                    ((float*)Cout)[(size_t)tok * C_ + colg[j]] = v;
                } else if (MODE == 2) {
                    ((ushort*)Cout)[(size_t)rowg * Nout + colg[j]] = f2b(gelu_exact(v));
                } else {
                    v += ((const float*)resid)[(size_t)rowg * Nout + colg[j]];
                    ((float*)Cout)[(size_t)rowg * Nout + colg[j]] = v;
                }
            }
        }
    }
}

// ---------------- MFMA windowed attention v4 --------------------------------
// Block = (window, head), 4 waves, mi-tiles strided across waves.
// K,V staged in LDS (coalesced glds16, source-swizzled); Q frags direct from
// global (L2-hot via XCD swizzle); bias+mask+OOB fused in MFMA-layout u32
// table (14 coalesced dwords/mi); no max-reduce; barrier-free main loop.
#define KOFF 0
#define VOFF 7168       // 128 rows x 64B (rows 112..127 stay zero)
#define POFF 15360      // Pl[4][16][136] ushort
#define SMEM_BYTES 32768
__global__ __launch_bounds__(256)
void attn_mfma(const ushort* __restrict__ qkv, const uint* __restrict__ Tb2,
               ushort* __restrict__ attn_out) {
    __shared__ __align__(16) char smem[SMEM_BYTES];
    ushort (*Pl)[16][136] = (ushort (*)[16][136])(smem + POFF);
    // un-swizzle: b = wid%8 + 8*hh + 64*(wid/8)  (heads of a window share XCD)
    const int b    = blockIdx.x;
    const int wid  = (b & 7) + ((b >> 6) << 3);
    const int hh   = (b >> 3) & 7;
    const int tid  = threadIdx.x;
    const int wv   = tid >> 6, lane = tid & 63;
    const int lrow = lane & 15, lgrp = lane >> 4;
    const float scale = 0.17677669529663687f;     // 1/sqrt(32)

    const ushort* base = qkv + (size_t)wid * N_ * 768 + hh * 32;
    const int rem = wid & 255;
    const int pat = (((rem >> 6) == 3) ? 1 : 0) | ((((rem >> 3) & 7) == 7) ? 2 : 0)
                  | (((rem & 7) == 7) ? 4 : 0);
    const uint* tb2 = Tb2 + (size_t)((pat * 8 + hh) * 7) * 14 * 64 + lane;

    // zero V pad rows + Pl
    {
        uint4 z = {0, 0, 0, 0};
        uint4* l4 = (uint4*)(smem + 14336);
        for (int i = tid; i < (SMEM_BYTES - 14336) / 16; i += 256) l4[i] = z;
    }
    __syncthreads();

    // stage K,V: 112 rows (rows >97 clamped), 64B/row = 4 chunks,
    // source chunk pre-swizzled with (row&3) so LDS stays linear.
    #pragma unroll
    for (int sect = 0; sect < 2; ++sect) {
        char* dstbase = smem + sect * 7168;
        const ushort* src = base + 256 + sect * 256;
        for (int c = tid; c < 448; c += 256) {
            int r = c >> 2; if (r > 97) r = 97;
            int cc = c & 3;
            glds16(src + (size_t)r * 768 + ((cc ^ (r & 3)) * 8), dstbase + c * 16);
        }
    }
    __syncthreads();   // drains vmcnt before barrier

    const int swz = (lgrp ^ (lrow & 3)) << 4;   // 16B-chunk swizzle for K reads

    // K fragments from LDS (A-frag layout: row=lrow, k-chunk=lgrp)
    bf16x8 kf[7];
    #pragma unroll
    for (int nj = 0; nj < 7; ++nj)
        kf[nj] = *(const bf16x8*)(smem + KOFF + (nj * 16 + lrow) * 64 + swz);

    // V B-frags: lane holds V[kt*32+lgrp*8+t][dt*16+lrow], scalar reads (one-time)
    bf16x8 vf[2][4];
    #pragma unroll
    for (int dt = 0; dt < 2; ++dt)
        #pragma unroll
        for (int kt = 0; kt < 4; ++kt) {
            bf16x8 tmp;
            #pragma unroll
            for (int t = 0; t < 8; ++t) {
                int R = kt * 32 + lgrp * 8 + t;
                int q = dt * 2 + (lrow >> 3);
                tmp[t] = *(const short*)(smem + VOFF + R * 64 +
                                         ((q ^ (t & 3)) << 4) + ((lrow & 7) << 1));
            }
            vf[dt][kt] = tmp;
        }

    for (int mi = wv; mi < 7; mi += 4) {
        const int ibase = mi * 16;

        // bias table words first (coalesced, latency hides under MFMAs)
        uint tw[14];
        const uint* tbm = tb2 + mi * 14 * 64;
        #pragma unroll
        for (int u = 0; u < 14; ++u) tw[u] = tbm[u * 64];

        bf16x8 qf = *(const bf16x8*)(base + (size_t)(ibase + lrow) * 768 + lgrp * 8);

        f32x4 s[7];
        #pragma unroll
        for (int nj = 0; nj < 7; ++nj) {
            f32x4 z = {0.f, 0.f, 0.f, 0.f};
            s[nj] = __builtin_amdgcn_mfma_f32_16x16x32_bf16(qf, kf[nj], z, 0, 0, 0);
        }

        // scale + fused bias/mask/OOB (baked -1e30), then exp without max
        #pragma unroll
        for (int nj = 0; nj < 7; ++nj) {
            #pragma unroll
            for (int r = 0; r < 4; ++r) {
                uint w = tw[nj * 2 + (r >> 1)];
                ushort hb = (r & 1) ? (ushort)(w >> 16) : (ushort)(w & 0xffff);
                s[nj][r] = s[nj][r] * scale + b2f(hb);
            }
        }

        float rinv[4];
        #pragma unroll
        for (int r = 0; r < 4; ++r) {
            float acc = 0.f;
            #pragma unroll
            for (int nj = 0; nj < 7; ++nj) {
                float p = __expf(s[nj][r]);
                s[nj][r] = p;
                acc += p;
            }
            #pragma unroll
            for (int o = 1; o < 16; o <<= 1) acc += __shfl_xor(acc, o);
            rinv[r] = 1.f / acc;
        }

        // P tile to this wave's private LDS slice (cols >=112 stay zero)
        #pragma unroll
        for (int nj = 0; nj < 7; ++nj)
            #pragma unroll
            for (int r = 0; r < 4; ++r)
                Pl[wv][lgrp * 4 + r][nj * 16 + lrow] = f2b(s[nj][r] * rinv[r]);

        // PV: O[i][d] = sum_j P[i][j] V[j][d]
        f32x4 o0 = {0.f, 0.f, 0.f, 0.f}, o1 = {0.f, 0.f, 0.f, 0.f};
        #pragma unroll
        for (int kt = 0; kt < 4; ++kt) {
            bf16x8 pf = *(const bf16x8*)(&Pl[wv][lrow][kt * 32 + lgrp * 8]);
            o0 = __builtin_amdgcn_mfma_f32_16x16x32_bf16(pf, vf[0][kt], o0, 0, 0, 0);
            o1 = __builtin_amdgcn_mfma_f32_16x16x32_bf16(pf, vf[1][kt], o1, 0, 0, 0);
        }

        #pragma unroll
        for (int r = 0; r < 4; ++r) {
            int i = ibase + lgrp * 4 + r;
            if (i < N_) {
                size_t rb = ((size_t)(wid * N_ + i)) * C_ + hh * 32;
                attn_out[rb + lrow]      = f2b(o0[r]);
                attn_out[rb + 16 + lrow] = f2b(o1[r]);
            }
        }
    }
}

// ---------------------------------------------------------------------------
extern "C" void kernel_launch(void* const* d_in, const int* in_sizes, int n_in,
                              void* d_out, int out_size, void* d_ws, size_t ws_size,
                              hipStream_t stream) {
    const float* x      = (const float*)d_in[0];
    const float* qkv_w  = (const float*)d_in[1];
    const float* qkv_b  = (const float*)d_in[2];
    const float* proj_w = (const float*)d_in[3];
    const float* proj_b = (const float*)d_in[4];
    const float* rpb    = (const float*)d_in[5];
    const float* ln1_g  = (const float*)d_in[6];
    const float* ln1_b  = (const float*)d_in[7];
    const float* ln2_g  = (const float*)d_in[8];
    const float* ln2_b  = (const float*)d_in[9];
    const float* fc1_w  = (const float*)d_in[10];
    const float* fc1_b  = (const float*)d_in[11];
    const float* fc2_w  = (const float*)d_in[12];
    const float* fc2_b  = (const float*)d_in[13];
    const int*   rel_idx= (const int*)d_in[14];
    const float* mask   = (const float*)d_in[15];
    float* out = (float*)d_out;

    char* ws = (char*)d_ws;
    ushort* regionA = (ushort*)ws;                                   // qkv/hidden bf16
    ushort* regionB = (ushort*)(ws + (size_t)TOK * HID * 2);         // win/attn_out/h2 bf16
    ushort* wq  = (ushort*)(ws + (size_t)TOK * HID * 2 + (size_t)TOK * C_ * 2);
    ushort* wp  = wq + 768 * 256;
    ushort* w1  = wp + 256 * 256;
    ushort* w2  = w1 + HID * 256;
    uint*   Tb2 = (uint*)(w2 + 256 * HID);                           // 1.6 MB

    // K0: bias+mask table + fused weight converts
    tbl_kernel<<<(TB2_WORDS + 255) / 256, 256, 0, stream>>>(rel_idx, rpb, mask, Tb2);
    {
        dim3 g(256, 4);
        f2b4_kernel<<<g, 256, 0, stream>>>(qkv_w, wq, 768 * 256,
                                           proj_w, wp, 256 * 256,
                                           fc1_w, w1, HID * 256,
                                           fc2_w, w2, 256 * HID);
    }

    // K1: LN1 + shift + window partition -> regionB bf16
    ln_kernel<true><<<TOK / 4, 256, 0, stream>>>(x, ln1_g, ln1_b, regionB, TOK);

    // K2: QKV GEMM -> regionA bf16 (50176 x 768)
    {
        dim3 g(TOK / 128, 768 / 128);
        gemm_bf16<0><<<g, 256, 0, stream>>>(regionB, wq, qkv_b, regionA, nullptr, TOK, 256, 768);
    }

    // K3: MFMA windowed attention -> regionB bf16
    attn_mfma<<<NWIN_TOT * NH_, 256, 0, stream>>>(regionA, Tb2, regionB);

    // K4: proj GEMM + window reverse + unshift + residual(x) -> out fp32
    {
        dim3 g(TOK / 128, 256 / 128);
        gemm_bf16<1><<<g, 256, 0, stream>>>(regionB, wp, proj_b, out, x, TOK, 256, 256);
    }

    // K5: LN2 -> regionB bf16
    ln_kernel<false><<<TOK / 4, 256, 0, stream>>>(out, ln2_g, ln2_b, regionB, TOK);

    // K6: fc1 + GELU -> regionA bf16 (50176 x 1024)
    {
        dim3 g(TOK / 128, HID / 128);
        gemm_bf16<2><<<g, 256, 0, stream>>>(regionB, w1, fc1_b, regionA, nullptr, TOK, 256, HID);
    }

    // K7: fc2 + residual (in place on out)
    {
        dim3 g(TOK / 128, 256 / 128);
        gemm_bf16<3><<<g, 256, 0, stream>>>(regionA, w2, fc2_b, out, out, TOK, HID, 256);
    }
}